// Round 2
// baseline (101.400 us; speedup 1.0000x reference)
//
#include <hip/hip_runtime.h>

// GaussianEdgeGuideV2: edge-guided 3x3 softmax filtering.
// mask: (8,64,128,128) fp32, edge: (8,1,64,64) fp32 -> out (8,64,128,128) fp32.
//
// R8 = R7 resubmitted verbatim (R7 bench was an infra failure: "MI355X
// container failed twice" -- no kernel verdict. Device-side audit found no
// OOB/hang/barrier hazard: all rows clamped, LDS writes in-bounds, uniform
// barriers, single graph-safe launch.)
//
// R7 theory: dur_us 84.5 = ~42.3us harness ws-poison fill (256MiB
// fillBufferAligned, ALL top-5 rocprof dispatches) + ~42us kernel.
// Kernel floor is ~12us (75MB @ 6.3TB/s) -> we're at ~28% of achievable BW.
// Blame: 24 f4 VMEM requests/thread (3x redundant row loads), depth-2 buf
// register dance serializing on ~900cy HBM latency with ~300cy of cover,
// and 48 ds_bpermute shuffles. Request/latency-bound, not BW-bound.
//
// Fix: stage each mask element into LDS exactly ONCE.
//   - m_s[4][10][128] (20KB): wave w reg-stages channel w, 5 coalesced
//     f4/thread, issued up-front and hidden under the edge/weight prologue.
//   - two 4-channel phases; phase-2 loads issued BEFORE phase-1 compute
//     (T14 async split) so their latency hides under ~1.2us of FMA work.
//   - compute reads the 3x6 window from LDS (b128 + 2 scalars per row):
//     no __shfl, no buf dance. VMEM loads/thread 24 -> 10.
//   - LDS 25.8KB, __launch_bounds__(256,4) -> 4 blocks/CU, all 1024 resident.
// Predict: kernel ~42 -> ~14-17us, dur_us -> ~56-59. absmax unchanged.

#define THETA 10.0f

constexpr int NB = 8;     // batch
constexpr int C  = 64;    // mask channels
constexpr int H  = 128, W = 128;
constexpr int EH = 64,  EW = 64;
constexpr int HW = H * W;

constexpr int ROWS = 8;   // output rows per block tile
constexpr int CG   = 8;   // channels per block (two LDS phases of 4)

// grid: x = C/CG = 8, y = H/ROWS = 16, z = NB = 8; block = 256
__global__ __launch_bounds__(256, 4) void geg_kernel(
    const float* __restrict__ mask,
    const float* __restrict__ edge,
    float* __restrict__ out)
{
    // upsampled-edge tile with zero border (the unfold's zero padding)
    __shared__ float e_s[ROWS + 2][W + 4];      // fill/read cols 0..W+1
    // mask tile: 4 channels x 10 rows (y0-1..y0+8, row-clamped) x 128 cols
    __shared__ float m_s[4][ROWS + 2][W];

    const int t     = threadIdx.x;
    const int cg    = blockIdx.x;
    const int ytile = blockIdx.y;
    const int n     = blockIdx.z;
    const int y0    = ytile * ROWS;

    // ---- compute geometry: 4 consecutive-x pixels in one row
    const int lane = t & 31;         // position within the 32-lane row group
    const int x4   = lane * 4;       // 0,4,...,124
    const int r    = t >> 5;         // 0..7
    const int gy   = y0 + r;

    // ---- staging geometry: wave w owns channel w (then w+4 in phase 2)
    const int wid  = t >> 6;         // wave id 0..3
    const int li   = t & 63;         // lane in wave
    const int srow = li >> 5;        // 0/1: which of the 2 rows per k-chunk
    const int scol = (li & 31) * 4;  // f4 column

    const int c0 = cg * CG;
    const float* mptr = mask + (size_t)(n * C + c0) * HW;

    // ---- phase-1 staging loads: each mask element exactly once, 5 f4 in
    //      flight per thread; latency hides under the prologue below.
    float4 st[5];
    int goff[5];
    #pragma unroll
    for (int k = 0; k < 5; ++k) {
        int row10 = 2 * k + srow;                        // m_s row 0..9
        int gr = min(max(y0 - 1 + row10, 0), H - 1);     // clamp: weight=0 there
        goff[k] = gr * W + scol;
        st[k] = *(const float4*)(mptr + wid * HW + goff[k]);
    }

    // ---- stage bilinear-upsampled edge rows [y0-1, y0+ROWS] x cols [-1, W]
    const float* eg = edge + n * (EH * EW);
    const float s = 63.0f / 127.0f;          // (EH-1)/(H-1)
    for (int idx = t; idx < (ROWS + 2) * (W + 2); idx += 256) {
        int rr = idx / (W + 2);
        int cc = idx - rr * (W + 2);
        int egy = y0 - 1 + rr;
        int egx = cc - 1;
        float v = 0.0f;
        if (egy >= 0 && egy < H && egx >= 0 && egx < W) {
            float ys = egy * s;
            float xs = egx * s;
            float yf = floorf(ys), xf = floorf(xs);
            int iy0 = (int)yf, ix0 = (int)xf;
            int iy1 = min(iy0 + 1, EH - 1), ix1 = min(ix0 + 1, EW - 1);
            float wy = ys - yf, wx = xs - xf;
            float tl = eg[iy0 * EW + ix0], tr = eg[iy0 * EW + ix1];
            float bl = eg[iy1 * EW + ix0], br = eg[iy1 * EW + ix1];
            float lv = tl + (bl - tl) * wy;
            float rv = tr + (br - tr) * wy;
            v = lv + (rv - lv) * wx;
        }
        e_s[rr][cc] = v;
    }
    __syncthreads();

    // ---- per-pixel softmax weights (OOB neighbors zeroed; denom keeps all 9)
    float w[4][9];
    #pragma unroll
    for (int p = 0; p < 4; ++p) {
        const int gx = x4 + p;
        const float c = e_s[r + 1][gx + 1];
        float a[9], sum = 0.0f;
        #pragma unroll
        for (int di = 0; di < 3; ++di) {
            #pragma unroll
            for (int dj = 0; dj < 3; ++dj) {
                float d = c - e_s[r + di][gx + dj];
                float e = __expf(-THETA * d * d);
                a[di * 3 + dj] = e;
                sum += e;
            }
        }
        const float inv = 1.0f / sum;
        #pragma unroll
        for (int di = 0; di < 3; ++di) {
            #pragma unroll
            for (int dj = 0; dj < 3; ++dj) {
                int ny = gy + di - 1, nx = gx + dj - 1;
                bool ok = (ny >= 0) & (ny < H) & (nx >= 0) & (nx < W);
                w[p][di * 3 + dj] = ok ? a[di * 3 + dj] * inv : 0.0f;
            }
        }
    }

    // ---- commit phase-1 tile to LDS (loads long since landed)
    #pragma unroll
    for (int k = 0; k < 5; ++k)
        *(float4*)&m_s[wid][2 * k + srow][scol] = st[k];
    __syncthreads();

    // ---- issue phase-2 loads NOW; hidden under phase-1 compute (T14 split)
    #pragma unroll
    for (int k = 0; k < 5; ++k)
        st[k] = *(const float4*)(mptr + (wid + 4) * HW + goff[k]);

    float* optr = out + (size_t)(n * C + c0) * HW + gy * W + x4;
    const int xm = max(x4 - 1, 0);       // clamped x-halo: weight is 0 there
    const int xp = min(x4 + 4, W - 1);

    // ---- phase-1 compute: channels c0..c0+3 from LDS
    #pragma unroll
    for (int ci = 0; ci < 4; ++ci) {
        float av[4] = {0.f, 0.f, 0.f, 0.f};
        #pragma unroll
        for (int di = 0; di < 3; ++di) {
            const float* mrow = m_s[ci][r + di];
            const float4 mid = *(const float4*)(mrow + x4);
            float m6[6] = { mrow[xm], mid.x, mid.y, mid.z, mid.w, mrow[xp] };
            #pragma unroll
            for (int p = 0; p < 4; ++p) {
                av[p] = fmaf(m6[p + 0], w[p][di * 3 + 0],
                        fmaf(m6[p + 1], w[p][di * 3 + 1],
                        fmaf(m6[p + 2], w[p][di * 3 + 2], av[p])));
            }
        }
        *(float4*)(optr + ci * HW) = make_float4(av[0], av[1], av[2], av[3]);
    }

    __syncthreads();   // all reads of m_s done -> safe to overwrite

    // ---- commit phase-2 tile (loads hidden under phase-1 compute)
    #pragma unroll
    for (int k = 0; k < 5; ++k)
        *(float4*)&m_s[wid][2 * k + srow][scol] = st[k];
    __syncthreads();

    // ---- phase-2 compute: channels c0+4..c0+7
    #pragma unroll
    for (int ci = 0; ci < 4; ++ci) {
        float av[4] = {0.f, 0.f, 0.f, 0.f};
        #pragma unroll
        for (int di = 0; di < 3; ++di) {
            const float* mrow = m_s[ci][r + di];
            const float4 mid = *(const float4*)(mrow + x4);
            float m6[6] = { mrow[xm], mid.x, mid.y, mid.z, mid.w, mrow[xp] };
            #pragma unroll
            for (int p = 0; p < 4; ++p) {
                av[p] = fmaf(m6[p + 0], w[p][di * 3 + 0],
                        fmaf(m6[p + 1], w[p][di * 3 + 1],
                        fmaf(m6[p + 2], w[p][di * 3 + 2], av[p])));
            }
        }
        *(float4*)(optr + (ci + 4) * HW) = make_float4(av[0], av[1], av[2], av[3]);
    }
}

extern "C" void kernel_launch(void* const* d_in, const int* in_sizes, int n_in,
                              void* d_out, int out_size, void* d_ws, size_t ws_size,
                              hipStream_t stream) {
    const float* mask = (const float*)d_in[0];
    const float* edge = (const float*)d_in[1];
    float* out = (float*)d_out;

    dim3 grid(C / CG, H / ROWS, NB);   // 8 x 16 x 8 = 1024 blocks
    dim3 block(256);
    geg_kernel<<<grid, block, 0, stream>>>(mask, edge, out);
}

// Round 3
// 85.932 us; speedup vs baseline: 1.1800x; 1.1800x over previous
//
#include <hip/hip_runtime.h>

// GaussianEdgeGuideV2: edge-guided 3x3 softmax filtering.
// mask: (8,64,128,128) fp32, edge: (8,1,64,64) fp32 -> out (8,64,128,128) fp32.
//
// R9 = instrumented revert to R6 (the 84.5us winner). Post-mortem of R7/R8
// (LDS stage-once, 101.4us, +17): 4 block-wide barriers each draining
// vmcnt(0) on in-flight phase loads, LDS round-trip per element, 8-way
// conflicted scalar halo ds_reads, and a 128-VGPR cap (launch_bounds ,4)
// holding st[5]+w[36] -> probable scratch spills. geg stayed <43us in
// rocprof top-5 both rounds, so dur_us composition is fill(~42) + geg + X;
// structural gambles without geg counters are blind. Revert + two
// zero-structural-risk micro-opts:
//   1) non-temporal f4 stores: out is write-once; keep 32MB of writes from
//      evicting the 3x-reused mask rows in L1/L2.
//   2) division-free e_s staging (2row x 128col mapping, no idx/130).
// Structure (identical to R6): depth-2 register prefetch, x-halo via
// 32-lane shuffles, ONE barrier, plain __launch_bounds__(256).
// Predict: dur_us ~82-85 (re-anchor, maybe -1..-3 from NT); absmax same.

#define THETA 10.0f

constexpr int NB = 8;     // batch
constexpr int C  = 64;    // mask channels
constexpr int H  = 128, W = 128;
constexpr int EH = 64,  EW = 64;

constexpr int ROWS = 8;   // output rows per block tile
constexpr int CG   = 8;   // channels per block (C/CG = 8 groups)

typedef float f4v __attribute__((ext_vector_type(4)));

// grid: x = C/CG = 8, y = H/ROWS = 16, z = NB = 8; block = 256
__global__ __launch_bounds__(256) void geg_kernel(
    const float* __restrict__ mask,
    const float* __restrict__ edge,
    float* __restrict__ out)
{
    // upsampled-edge tile with zero border (the unfold's zero padding)
    __shared__ float e_s[ROWS + 2][W + 4];   // fill/read cols 0..W+1

    const int t     = threadIdx.x;
    const int cg    = blockIdx.x;
    const int ytile = blockIdx.y;
    const int n     = blockIdx.z;
    const int y0    = ytile * ROWS;

    // ---- thread geometry: 4 consecutive-x pixels in one row
    const int lane = t & 31;         // position within the 32-lane row group
    const int x4   = lane * 4;       // 0,4,...,124
    const int r    = t >> 5;         // 0..7
    const int gy   = y0 + r;

    // clamped row offsets (OOB rows get zero weight; clamp keeps addr in-bounds)
    int rowoff[3];
    rowoff[0] = max(gy - 1, 0) * W + x4;
    rowoff[1] = gy * W + x4;
    rowoff[2] = min(gy + 1, H - 1) * W + x4;

    const int c0 = cg * CG;
    const float* mptr = mask + (size_t)(n * C + c0) * (H * W);

    // ---- issue ch0+ch1 loads NOW; the prologue below hides their latency
    float4 buf[2][3];
    #pragma unroll
    for (int i = 0; i < 3; ++i) {
        buf[0][i] = *(const float4*)(mptr + rowoff[i]);
        buf[1][i] = *(const float4*)(mptr + H * W + rowoff[i]);
    }

    // ---- stage bilinear-upsampled edge rows [y0-1, y0+ROWS] x cols [-1, W]
    //      division-free mapping: 2 rows x 128 cols per step
    const float* eg = edge + n * (EH * EW);
    const float s = 63.0f / 127.0f;          // (EH-1)/(H-1)
    const int rr0 = t >> 7;                  // 0/1
    const int cc0 = t & 127;
    #pragma unroll
    for (int rb = 0; rb < ROWS + 2; rb += 2) {
        const int rr = rb + rr0;
        for (int cc = cc0; cc < W + 2; cc += 128) {
            int egy = y0 - 1 + rr;
            int egx = cc - 1;
            float v = 0.0f;
            if (egy >= 0 && egy < H && egx >= 0 && egx < W) {
                float ys = egy * s;
                float xs = egx * s;
                float yf = floorf(ys), xf = floorf(xs);
                int iy0 = (int)yf, ix0 = (int)xf;
                int iy1 = min(iy0 + 1, EH - 1), ix1 = min(ix0 + 1, EW - 1);
                float wy = ys - yf, wx = xs - xf;
                float tl = eg[iy0 * EW + ix0], tr = eg[iy0 * EW + ix1];
                float bl = eg[iy1 * EW + ix0], br = eg[iy1 * EW + ix1];
                float lv = tl + (bl - tl) * wy;
                float rv = tr + (br - tr) * wy;
                v = lv + (rv - lv) * wx;
            }
            e_s[rr][cc] = v;
        }
    }
    __syncthreads();

    // ---- per-pixel softmax weights (OOB neighbors zeroed; denom keeps all 9)
    float w[4][9];
    #pragma unroll
    for (int p = 0; p < 4; ++p) {
        const int gx = x4 + p;
        const float c = e_s[r + 1][gx + 1];
        float a[9], sum = 0.0f;
        #pragma unroll
        for (int di = 0; di < 3; ++di) {
            #pragma unroll
            for (int dj = 0; dj < 3; ++dj) {
                float d = c - e_s[r + di][gx + dj];
                float e = __expf(-THETA * d * d);
                a[di * 3 + dj] = e;
                sum += e;
            }
        }
        const float inv = 1.0f / sum;
        #pragma unroll
        for (int di = 0; di < 3; ++di) {
            #pragma unroll
            for (int dj = 0; dj < 3; ++dj) {
                int ny = gy + di - 1, nx = gx + dj - 1;
                bool ok = (ny >= 0) & (ny < H) & (nx >= 0) & (nx < W);
                w[p][di * 3 + dj] = ok ? a[di * 3 + dj] * inv : 0.0f;
            }
        }
    }

    // ---- channel loop, depth-2 prefetch
    float* optr = out + (size_t)(n * C + c0) * (H * W) + gy * W + x4;

    #pragma unroll
    for (int ci = 0; ci < CG; ++ci) {
        float4 cur[3];
        #pragma unroll
        for (int i = 0; i < 3; ++i) cur[i] = buf[ci & 1][i];

        if (ci + 2 < CG) {
            #pragma unroll
            for (int i = 0; i < 3; ++i)
                buf[ci & 1][i] = *(const float4*)(mptr + (ci + 2) * (H * W) + rowoff[i]);
        }

        float av[4] = {0.f, 0.f, 0.f, 0.f};
        #pragma unroll
        for (int i = 0; i < 3; ++i) {
            // 6-wide row window; x-halo via shuffle in the 32-lane row group
            // (edge lanes get junk, but their weight is 0)
            float m6[6];
            m6[0] = __shfl_up(cur[i].w, 1, 32);
            m6[1] = cur[i].x; m6[2] = cur[i].y; m6[3] = cur[i].z; m6[4] = cur[i].w;
            m6[5] = __shfl_down(cur[i].x, 1, 32);
            #pragma unroll
            for (int p = 0; p < 4; ++p) {
                av[p] = fmaf(m6[p + 0], w[p][i * 3 + 0],
                        fmaf(m6[p + 1], w[p][i * 3 + 1],
                        fmaf(m6[p + 2], w[p][i * 3 + 2], av[p])));
            }
        }
        // non-temporal store: out is write-once, keep it out of L1/L2
        f4v v; v.x = av[0]; v.y = av[1]; v.z = av[2]; v.w = av[3];
        __builtin_nontemporal_store(v, (f4v*)(optr + ci * (H * W)));
    }
}

extern "C" void kernel_launch(void* const* d_in, const int* in_sizes, int n_in,
                              void* d_out, int out_size, void* d_ws, size_t ws_size,
                              hipStream_t stream) {
    const float* mask = (const float*)d_in[0];
    const float* edge = (const float*)d_in[1];
    float* out = (float*)d_out;

    dim3 grid(C / CG, H / ROWS, NB);   // 8 x 16 x 8 = 1024 blocks
    dim3 block(256);
    geg_kernel<<<grid, block, 0, stream>>>(mask, edge, out);
}